// Round 3
// baseline (381.655 us; speedup 1.0000x reference)
//
#include <hip/hip_runtime.h>
#include <stdint.h>

#define TT 64
#define NN 2048
#define EE 8192
#define DD 128
#define CAP 32

typedef __attribute__((ext_vector_type(8))) short bvec8;
typedef __attribute__((ext_vector_type(4))) float fvec4;

__device__ __forceinline__ float bf2f(uint16_t u){
  union { uint32_t i; float f; } v; v.i = ((uint32_t)u) << 16; return v.f;
}
__device__ __forceinline__ uint16_t f2bf(float f){
  union { float f; uint32_t i; } v; v.f = f;
  uint32_t r = v.i + 0x7fffu + ((v.i >> 16) & 1u);
  return (uint16_t)(r >> 16);
}
// packed f32x2 -> bf16x2 (RNE), single VALU instr
__device__ __forceinline__ uint32_t cvtpk(float lo, float hi){
  uint32_t r;
  asm("v_cvt_pk_bf16_f32 %0, %1, %2" : "=v"(r) : "v"(lo), "v"(hi));
  return r;
}
__device__ __forceinline__ fvec4 mfma16(bvec8 a, bvec8 b, fvec4 c){
  return __builtin_amdgcn_mfma_f32_16x16x32_bf16(a, b, c, 0, 0, 0);
}

// ---------------- CSR build (deterministic) ----------------
__global__ void k_fill(const int* __restrict__ dst, int* __restrict__ cnt, int* __restrict__ es){
  int tid = blockIdx.x * 256 + threadIdx.x;          // T*E threads
  int t = tid >> 13, e = tid & (EE - 1);
  int d = dst[tid];
  int row = t * NN + d;
  int pos = atomicAdd(&cnt[row], 1);
  if (pos < CAP) es[(size_t)row * CAP + pos] = e;
}

__global__ void k_sortconv(int* __restrict__ cnt, int* __restrict__ es, float* __restrict__ wcsr,
                           const int* __restrict__ srcA, const float* __restrict__ ewA){
  int row = blockIdx.x * 256 + threadIdx.x;          // T*N threads
  if (row >= TT * NN) return;
  int t = row >> 11;
  int c = cnt[row]; if (c > CAP) c = CAP;
  cnt[row] = c;
  int* p = es + (size_t)row * CAP;
  for (int i = 0; i < c; ++i){                        // selection sort ascending (deterministic order)
    int mi = i, mv = p[i];
    for (int j = i + 1; j < c; ++j){ int vj = p[j]; if (vj < mv){ mv = vj; mi = j; } }
    if (mi != i){ p[mi] = p[i]; p[i] = mv; }
  }
  const int* srcT = srcA + (size_t)t * EE;
  const float* ewT = ewA + (size_t)t * EE;
  float* wp = wcsr + (size_t)row * CAP;
  for (int i = 0; i < c; ++i){
    int e = p[i];
    p[i] = srcT[e];
    wp[i] = ewT[e];
  }
}

// ---------------- weight packing (hi/lo bf16 split, MFMA B-fragment order) ----------------
__global__ void k_prep(const float* __restrict__ Wp, const float* __restrict__ Wq,
                       const float* __restrict__ Wk, const float* __restrict__ Wv,
                       const float* __restrict__ bq, const float* __restrict__ bk,
                       const float* __restrict__ bv,
                       uint16_t* __restrict__ WpHi, uint16_t* __restrict__ WpLo,
                       uint16_t* __restrict__ QHi, float* __restrict__ biasPad){
  int tid = blockIdx.x * 256 + threadIdx.x;
  if (tid < 2048){
    int lane = tid & 63, kc = (tid >> 6) & 3, ct = tid >> 8;
    int g = lane >> 4, l15 = lane & 15;
    #pragma unroll
    for (int j = 0; j < 8; ++j){
      int k = kc * 32 + g * 8 + j;
      int col = ct * 16 + l15;
      float v = Wp[k * DD + col];
      uint16_t h = f2bf(v);
      WpHi[(size_t)tid * 8 + j] = h;
      WpLo[(size_t)tid * 8 + j] = f2bf(v - bf2f(h));
    }
  } else if (tid < 2048 + 9216){
    int idx = tid - 2048;
    int lane = idx & 63, kc = (idx >> 6) & 3, t2 = idx >> 8;  // t2 = m*12+h
    int h = t2 % 12, m = t2 / 12;
    const float* W = (m == 0) ? Wq : (m == 1) ? Wk : Wv;
    int g = lane >> 4, l15 = lane & 15;
    #pragma unroll
    for (int j = 0; j < 8; ++j){
      int k = kc * 32 + g * 8 + j;
      float v = (l15 < 10) ? W[k * 120 + h * 10 + l15] : 0.f;
      QHi[(size_t)idx * 8 + j] = f2bf(v);
    }
  } else if (tid < 2048 + 9216 + 576){
    int idx = tid - (2048 + 9216);
    int m = idx / 192, rest = idx % 192;
    int h = rest / 16, d = rest % 16;
    const float* B = (m == 0) ? bq : (m == 1) ? bk : bv;
    biasPad[idx] = (d < 10) ? B[h * 10 + d] : 0.f;
  }
}

// ---------------- x0 = emb[ids] (f32 -> bf16) ----------------
__global__ void k_gather(const int* __restrict__ ids, const float* __restrict__ emb,
                         uint16_t* __restrict__ x){
  int tid = blockIdx.x * 256 + threadIdx.x;          // T*N*16
  int row = tid >> 4, c8 = tid & 15;
  int id = ids[row];
  const float* er = emb + (size_t)id * DD + c8 * 8;
  float4 a = *(const float4*)er;
  float4 b = *(const float4*)(er + 4);
  union { uint32_t u[4]; bvec8 v; } o;
  o.u[0] = cvtpk(a.x, a.y);
  o.u[1] = cvtpk(a.z, a.w);
  o.u[2] = cvtpk(b.x, b.y);
  o.u[3] = cvtpk(b.z, b.w);
  *(bvec8*)(x + (size_t)row * DD + c8 * 8) = o.v;
}

// ---------------- fused propagate: n_hat = x + scatter; out = n_hat@Wp + bp ----------------
__global__ __launch_bounds__(256, 4) void k_prop(const uint16_t* __restrict__ xin,
    uint16_t* __restrict__ xout, const int* __restrict__ cnt, const int* __restrict__ csrS,
    const float* __restrict__ csrW, const uint16_t* __restrict__ WHi,
    const uint16_t* __restrict__ WLo, const float* __restrict__ bp, int topt){
  __shared__ uint16_t lds[64 * 136];
  int vb = blockIdx.x;
  int b = ((vb & 7) << 8) | (vb >> 3);                // XCD swizzle: one t handled on one XCD
  int t = b >> 5, n0 = (b & 31) << 6;
  int tid = threadIdx.x, w = tid >> 6, lane = tid & 63, g = lane >> 4, l15 = lane & 15;
  const uint16_t* xt = xin + (size_t)t * NN * DD;
  int baseRow = t * NN + n0 + w * 16;
  int myc = (lane < 16) ? cnt[baseRow + lane] : 0;
  // phase 1: n_hat rows -> LDS (bf16); 8-wide predicated gather pipeline per row
  #pragma unroll 2
  for (int i = 0; i < 16; ++i){
    int r = w * 16 + i;
    int n = n0 + r;
    int rowg = baseRow + i;
    uint32_t u = *(const uint32_t*)(xt + (size_t)n * DD + (lane << 1));
    int c = __shfl(myc, i);
    const int* ss = csrS + (size_t)rowg * CAP;
    const float* ww = csrW + (size_t)rowg * CAP;
    int4 sA = *(const int4*)ss;
    int4 sB = *(const int4*)(ss + 4);
    float4 wA = *(const float4*)ww;
    float4 wB = *(const float4*)(ww + 4);
    int sj[8] = {sA.x, sA.y, sA.z, sA.w, sB.x, sB.y, sB.z, sB.w};
    float wj[8] = {wA.x, wA.y, wA.z, wA.w, wB.x, wB.y, wB.z, wB.w};
    uint32_t xs[8];
    float wf[8];
    #pragma unroll
    for (int j = 0; j < 8; ++j){
      int s = (j < c) ? sj[j] : n;         // clamp garbage indices, zero the weight
      wf[j] = (j < c) ? wj[j] : 0.f;
      xs[j] = *(const uint32_t*)(xt + (size_t)s * DD + (lane << 1));
    }
    float a0 = bf2f((uint16_t)(u & 0xffffu));
    float a1 = bf2f((uint16_t)(u >> 16));
    #pragma unroll
    for (int j = 0; j < 8; ++j){
      a0 = fmaf(wf[j], bf2f((uint16_t)(xs[j] & 0xffffu)), a0);
      a1 = fmaf(wf[j], bf2f((uint16_t)(xs[j] >> 16)), a1);
    }
    if (c > 8){                             // rare tail
      for (int j = 8; j < c; ++j){
        int s = ss[j];
        float wt = ww[j];
        uint32_t us = *(const uint32_t*)(xt + (size_t)s * DD + (lane << 1));
        a0 = fmaf(wt, bf2f((uint16_t)(us & 0xffffu)), a0);
        a1 = fmaf(wt, bf2f((uint16_t)(us >> 16)), a1);
      }
    }
    *(uint32_t*)&lds[r * 136 + (lane << 1)] = cvtpk(a0, a1);
  }
  __syncthreads();
  // phase 2: GEMM [64x128] @ [128x128], wave w -> row-tile w
  bvec8 afr[4];
  int arow = w * 16 + l15;
  #pragma unroll
  for (int kc = 0; kc < 4; ++kc)
    afr[kc] = *(const bvec8*)&lds[arow * 136 + kc * 32 + g * 8];
  fvec4 acc[8];
  #pragma unroll
  for (int i = 0; i < 8; ++i) acc[i] = fvec4{0.f, 0.f, 0.f, 0.f};
  #pragma unroll
  for (int kc = 0; kc < 4; ++kc){
    #pragma unroll
    for (int ct = 0; ct < 8; ++ct){
      size_t base = ((size_t)(ct * 4 + kc) * 64 + lane) * 8;
      acc[ct] = mfma16(afr[kc], *(const bvec8*)&WHi[base], acc[ct]);
      acc[ct] = mfma16(afr[kc], *(const bvec8*)&WLo[base], acc[ct]);
    }
  }
  __syncthreads();
  // epilogue: C + bias -> bf16 back into LDS
  #pragma unroll
  for (int ct = 0; ct < 8; ++ct){
    int col = ct * 16 + l15;
    float bias = bp[col];
    uint32_t c01 = cvtpk(acc[ct][0] + bias, acc[ct][1] + bias);
    uint32_t c23 = cvtpk(acc[ct][2] + bias, acc[ct][3] + bias);
    int r = w * 16 + g * 4;
    lds[(r + 0) * 136 + col] = (uint16_t)c01;
    lds[(r + 1) * 136 + col] = (uint16_t)(c01 >> 16);
    lds[(r + 2) * 136 + col] = (uint16_t)c23;
    lds[(r + 3) * 136 + col] = (uint16_t)(c23 >> 16);
  }
  __syncthreads();
  // store (topt: last round writes [n][t][d] for attention)
  #pragma unroll
  for (int p = 0; p < 4; ++p){
    int chunk = p * 256 + tid, r = chunk >> 4, c8 = chunk & 15;
    bvec8 v = *(const bvec8*)&lds[r * 136 + c8 * 8];
    size_t dstoff;
    if (topt == 0) dstoff = ((size_t)t * NN + n0 + r) * DD + c8 * 8;
    else           dstoff = (((size_t)(n0 + r)) * TT + t) * DD + c8 * 8;
    *(bvec8*)(xout + dstoff) = v;
  }
}

// ---------------- fused QKV + attention + partial mean ----------------
// Head-per-wave: wave w handles heads {w, 4+w, 8+w}. All LDS traffic is
// wave-private -> ZERO __syncthreads in the kernel; waves drift freely.
// Per-wave LDS: Kw[64][18], Qw[64][18] (frag-read conflict-free stride),
// Vt[16][68], Pw[16][68] (16B-chunk XOR swizzle, b64-packed writes).
__global__ __launch_bounds__(256, 4) void k_attn(const uint16_t* __restrict__ x3,
    const uint16_t* __restrict__ QHi, const float* __restrict__ biasPad,
    float* __restrict__ partials){
  __shared__ uint16_t ldsA[4][4480];                  // 35840 B -> 4 blocks/CU
  int n = blockIdx.x;
  int tid = threadIdx.x, w = tid >> 6, lane = tid & 63, g = lane >> 4, l15 = lane & 15;
  uint16_t* Kw = &ldsA[w][0];
  uint16_t* Qw = &ldsA[w][1152];
  uint16_t* Vt = &ldsA[w][2304];
  uint16_t* Pw = &ldsA[w][3392];
  const uint16_t* xr = x3 + (size_t)n * TT * DD;
  const int r7 = l15 & 7;
  const float CSC = 0.31622776601683794f * 1.4426950408889634f;  // (1/sqrt(10))*log2(e)

  for (int pass = 0; pass < 3; ++pass){
    int h = pass * 4 + w;
    // ---- QKV GEMM for head h (hi-only weights; zero-padded cols 10..15) ----
    fvec4 acc[12];                                    // [m*4+ti]
    #pragma unroll
    for (int i = 0; i < 12; ++i) acc[i] = fvec4{0.f, 0.f, 0.f, 0.f};
    #pragma unroll
    for (int kc = 0; kc < 4; ++kc){
      bvec8 B0 = *(const bvec8*)&QHi[((size_t)((0 * 12 + h) * 4 + kc) * 64 + lane) * 8];
      bvec8 B1 = *(const bvec8*)&QHi[((size_t)((1 * 12 + h) * 4 + kc) * 64 + lane) * 8];
      bvec8 B2 = *(const bvec8*)&QHi[((size_t)((2 * 12 + h) * 4 + kc) * 64 + lane) * 8];
      #pragma unroll
      for (int ti = 0; ti < 4; ++ti){
        bvec8 a = *(const bvec8*)&xr[(ti * 16 + l15) * DD + kc * 32 + g * 8];
        acc[0 * 4 + ti] = mfma16(a, B0, acc[0 * 4 + ti]);
        acc[1 * 4 + ti] = mfma16(a, B1, acc[1 * 4 + ti]);
        acc[2 * 4 + ti] = mfma16(a, B2, acc[2 * 4 + ti]);
      }
    }
    float bqv = biasPad[(0 * 12 + h) * 16 + l15];
    float bkv = biasPad[(1 * 12 + h) * 16 + l15];
    float bvv = biasPad[(2 * 12 + h) * 16 + l15];
    #pragma unroll
    for (int ti = 0; ti < 4; ++ti){
      int rb = ti * 16 + g * 4;
      {  // Q rows -> Qw[t][d]
        fvec4 aq = acc[0 * 4 + ti];
        uint32_t p01 = cvtpk(aq[0] + bqv, aq[1] + bqv);
        uint32_t p23 = cvtpk(aq[2] + bqv, aq[3] + bqv);
        Qw[(rb + 0) * 18 + l15] = (uint16_t)p01;
        Qw[(rb + 1) * 18 + l15] = (uint16_t)(p01 >> 16);
        Qw[(rb + 2) * 18 + l15] = (uint16_t)p23;
        Qw[(rb + 3) * 18 + l15] = (uint16_t)(p23 >> 16);
      }
      {  // K rows -> Kw[s][d]
        fvec4 ak = acc[1 * 4 + ti];
        uint32_t p01 = cvtpk(ak[0] + bkv, ak[1] + bkv);
        uint32_t p23 = cvtpk(ak[2] + bkv, ak[3] + bkv);
        Kw[(rb + 0) * 18 + l15] = (uint16_t)p01;
        Kw[(rb + 1) * 18 + l15] = (uint16_t)(p01 >> 16);
        Kw[(rb + 2) * 18 + l15] = (uint16_t)p23;
        Kw[(rb + 3) * 18 + l15] = (uint16_t)(p23 >> 16);
      }
      {  // V -> Vt[d][s] (b64 packed, chunk-swizzled by row)
        fvec4 av = acc[2 * 4 + ti];
        uint32_t p01 = cvtpk(av[0] + bvv, av[1] + bvv);
        uint32_t p23 = cvtpk(av[2] + bvv, av[3] + bvv);
        int e = ti * 16 + g * 4;
        int ch = (e >> 3) ^ r7;
        uint2 val; val.x = p01; val.y = p23;
        *(uint2*)&Vt[l15 * 68 + (ch << 3) + (e & 7)] = val;
      }
    }
    // ---- attention for head h; S^T via mfma(K,Q); softmax s-axis in-lane ----
    bvec8 zf = bvec8{};
    bvec8 kfr[4];
    #pragma unroll
    for (int si = 0; si < 4; ++si)
      kfr[si] = (g < 2) ? *(const bvec8*)&Kw[(si * 16 + l15) * 18 + g * 8] : zf;
    float csum = 0.f;
    #pragma unroll
    for (int ti = 0; ti < 4; ++ti){
      bvec8 qf = (g < 2) ? *(const bvec8*)&Qw[(ti * 16 + l15) * 18 + g * 8] : zf;
      fvec4 p[4];
      #pragma unroll
      for (int si = 0; si < 4; ++si)
        p[si] = mfma16(kfr[si], qf, fvec4{0.f, 0.f, 0.f, 0.f});
      // exp without rowmax: scores O(0.1); softmax shift-invariant -> exact
      float s = 0.f;
      #pragma unroll
      for (int si = 0; si < 4; ++si)
        #pragma unroll
        for (int rg = 0; rg < 4; ++rg){
          float pv = exp2f(p[si][rg] * CSC);
          p[si][rg] = pv;
          s += pv;
        }
      s += __shfl_xor(s, 16);
      s += __shfl_xor(s, 32);
      float rinv = __builtin_amdgcn_rcpf(s);
      // P^T tile -> Pw[t-local][s] (b64 packed, swizzled), normalized
      #pragma unroll
      for (int si = 0; si < 4; ++si){
        uint32_t a = cvtpk(p[si][0] * rinv, p[si][1] * rinv);
        uint32_t b = cvtpk(p[si][2] * rinv, p[si][3] * rinv);
        int e = si * 16 + g * 4;
        int ch = (e >> 3) ^ r7;
        uint2 val; val.x = a; val.y = b;
        *(uint2*)&Pw[l15 * 68 + (ch << 3) + (e & 7)] = val;
      }
      // PV: O[t-local][d=l15], accumulate column sums
      fvec4 o = fvec4{0.f, 0.f, 0.f, 0.f};
      #pragma unroll
      for (int kc = 0; kc < 2; ++kc){
        int ch = ((kc * 32 + g * 8) >> 3) ^ r7;
        bvec8 pa = *(const bvec8*)&Pw[l15 * 68 + (ch << 3)];
        bvec8 vb = *(const bvec8*)&Vt[l15 * 68 + (ch << 3)];
        o = mfma16(pa, vb, o);
      }
      csum += o[0] + o[1] + o[2] + o[3];
    }
    csum += __shfl_xor(csum, 16);
    csum += __shfl_xor(csum, 32);
    if (g == 0 && l15 < 10)
      partials[(size_t)n * 120 + h * 10 + l15] = csum;
  }
}

// ---------------- deterministic reductions ----------------
__global__ void k_reduce(const float* __restrict__ partials, float* __restrict__ agg){
  __shared__ float red[256];
  int c = blockIdx.x, tid = threadIdx.x;
  float s = 0.f;
  for (int b = tid; b < NN; b += 256) s += partials[(size_t)b * 120 + c];
  red[tid] = s;
  __syncthreads();
  for (int st = 128; st > 0; st >>= 1){
    if (tid < st) red[tid] += red[tid + st];
    __syncthreads();
  }
  if (tid == 0) agg[c] = red[0] * (1.0f / (float)(NN * TT));
}

__global__ void k_final(const float* __restrict__ agg, const float* __restrict__ Wo,
                        const float* __restrict__ bo, float* __restrict__ out){
  __shared__ float r0[128], r1[128];
  int j = threadIdx.x;
  float a = (j < 120) ? agg[j] : 0.f;
  r0[j] = (j < 120) ? a * Wo[2 * j] : 0.f;
  r1[j] = (j < 120) ? a * Wo[2 * j + 1] : 0.f;
  __syncthreads();
  for (int st = 64; st > 0; st >>= 1){
    if (j < st){ r0[j] += r0[j + st]; r1[j] += r1[j + st]; }
    __syncthreads();
  }
  if (j == 0){ out[0] = r0[0] + bo[0]; out[1] = r1[0] + bo[1]; }
}

extern "C" void kernel_launch(void* const* d_in, const int* in_sizes, int n_in,
                              void* d_out, int out_size, void* d_ws, size_t ws_size,
                              hipStream_t stream){
  const int*   node_ids = (const int*)d_in[0];
  const int*   srcA     = (const int*)d_in[1];
  const int*   dstA     = (const int*)d_in[2];
  const float* ew       = (const float*)d_in[3];
  const float* emb      = (const float*)d_in[4];
  const float* Wp       = (const float*)d_in[5];
  const float* bp       = (const float*)d_in[6];
  const float* Wq       = (const float*)d_in[7];
  const float* bq       = (const float*)d_in[8];
  const float* Wk       = (const float*)d_in[9];
  const float* bk       = (const float*)d_in[10];
  const float* Wv       = (const float*)d_in[11];
  const float* bv       = (const float*)d_in[12];
  const float* Wo       = (const float*)d_in[13];
  const float* bo       = (const float*)d_in[14];

  char* p = (char*)d_ws;
  auto alloc = [&](size_t bytes) -> char* {
    char* r = p; p += (bytes + 255) & ~(size_t)255; return r;
  };
  uint16_t* xA    = (uint16_t*)alloc((size_t)TT * NN * DD * 2);
  uint16_t* xB    = (uint16_t*)alloc((size_t)TT * NN * DD * 2);
  int*      cnt   = (int*)alloc((size_t)TT * NN * 4);
  int*      es    = (int*)alloc((size_t)TT * NN * CAP * 4);
  float*    wcsr  = (float*)alloc((size_t)TT * NN * CAP * 4);
  uint16_t* WpHi  = (uint16_t*)alloc(2048 * 8 * 2);
  uint16_t* WpLo  = (uint16_t*)alloc(2048 * 8 * 2);
  uint16_t* QHi   = (uint16_t*)alloc(9216 * 8 * 2);
  float*    biasP = (float*)alloc(576 * 4);
  float*    parts = (float*)alloc((size_t)NN * 120 * 4);
  float*    agg   = (float*)alloc(120 * 4);

  hipMemsetAsync(cnt, 0, (size_t)TT * NN * 4, stream);
  k_fill<<<TT * EE / 256, 256, 0, stream>>>(dstA, cnt, es);
  k_sortconv<<<TT * NN / 256, 256, 0, stream>>>(cnt, es, wcsr, srcA, ew);
  k_prep<<<47, 256, 0, stream>>>(Wp, Wq, Wk, Wv, bq, bk, bv, WpHi, WpLo, QHi, biasP);
  k_gather<<<TT * NN * 16 / 256, 256, 0, stream>>>(node_ids, emb, xA);
  k_prop<<<2048, 256, 0, stream>>>(xA, xB, cnt, es, wcsr, WpHi, WpLo, bp, 0);
  k_prop<<<2048, 256, 0, stream>>>(xB, xA, cnt, es, wcsr, WpHi, WpLo, bp, 0);
  k_prop<<<2048, 256, 0, stream>>>(xA, xB, cnt, es, wcsr, WpHi, WpLo, bp, 1);
  k_attn<<<NN, 256, 0, stream>>>(xB, QHi, biasP, parts);
  k_reduce<<<120, 256, 0, stream>>>(parts, agg);
  k_final<<<1, 128, 0, stream>>>(agg, Wo, bo, (float*)d_out);
}

// Round 4
// 319.416 us; speedup vs baseline: 1.1949x; 1.1949x over previous
//
#include <hip/hip_runtime.h>
#include <stdint.h>

#define TT 64
#define NN 2048
#define EE 8192
#define DD 128
#define CAP 32

typedef __attribute__((ext_vector_type(8))) short bvec8;
typedef __attribute__((ext_vector_type(4))) float fvec4;

__device__ __forceinline__ float bf2f(uint16_t u){
  union { uint32_t i; float f; } v; v.i = ((uint32_t)u) << 16; return v.f;
}
__device__ __forceinline__ uint16_t f2bf(float f){
  union { float f; uint32_t i; } v; v.f = f;
  uint32_t r = v.i + 0x7fffu + ((v.i >> 16) & 1u);
  return (uint16_t)(r >> 16);
}
// packed f32x2 -> bf16x2 (RNE), single VALU instr
__device__ __forceinline__ uint32_t cvtpk(float lo, float hi){
  uint32_t r;
  asm("v_cvt_pk_bf16_f32 %0, %1, %2" : "=v"(r) : "v"(lo), "v"(hi));
  return r;
}
__device__ __forceinline__ fvec4 mfma16(bvec8 a, bvec8 b, fvec4 c){
  return __builtin_amdgcn_mfma_f32_16x16x32_bf16(a, b, c, 0, 0, 0);
}

// ---------------- CSR build (deterministic) ----------------
__global__ void k_fill(const int* __restrict__ dst, int* __restrict__ cnt, int* __restrict__ es){
  int tid = blockIdx.x * 256 + threadIdx.x;          // T*E threads
  int t = tid >> 13, e = tid & (EE - 1);
  int d = dst[tid];
  int row = t * NN + d;
  int pos = atomicAdd(&cnt[row], 1);
  if (pos < CAP) es[(size_t)row * CAP + pos] = e;
}

__global__ void k_sortconv(int* __restrict__ cnt, int* __restrict__ es, float* __restrict__ wcsr,
                           const int* __restrict__ srcA, const float* __restrict__ ewA){
  int row = blockIdx.x * 256 + threadIdx.x;          // T*N threads
  if (row >= TT * NN) return;
  int t = row >> 11;
  int c = cnt[row]; if (c > CAP) c = CAP;
  cnt[row] = c;
  int* p = es + (size_t)row * CAP;
  for (int i = 0; i < c; ++i){                        // selection sort ascending (deterministic order)
    int mi = i, mv = p[i];
    for (int j = i + 1; j < c; ++j){ int vj = p[j]; if (vj < mv){ mv = vj; mi = j; } }
    if (mi != i){ p[mi] = p[i]; p[i] = mv; }
  }
  const int* srcT = srcA + (size_t)t * EE;
  const float* ewT = ewA + (size_t)t * EE;
  float* wp = wcsr + (size_t)row * CAP;
  for (int i = 0; i < c; ++i){
    int e = p[i];
    p[i] = srcT[e];
    wp[i] = ewT[e];
  }
}

// ---------------- weight packing (hi/lo bf16 split, MFMA B-fragment order) ----------------
__global__ void k_prep(const float* __restrict__ Wp, const float* __restrict__ Wq,
                       const float* __restrict__ Wk, const float* __restrict__ Wv,
                       const float* __restrict__ bq, const float* __restrict__ bk,
                       const float* __restrict__ bv,
                       uint16_t* __restrict__ WpHi, uint16_t* __restrict__ WpLo,
                       uint16_t* __restrict__ QHi, float* __restrict__ biasPad){
  int tid = blockIdx.x * 256 + threadIdx.x;
  if (tid < 2048){
    int lane = tid & 63, kc = (tid >> 6) & 3, ct = tid >> 8;
    int g = lane >> 4, l15 = lane & 15;
    #pragma unroll
    for (int j = 0; j < 8; ++j){
      int k = kc * 32 + g * 8 + j;
      int col = ct * 16 + l15;
      float v = Wp[k * DD + col];
      uint16_t h = f2bf(v);
      WpHi[(size_t)tid * 8 + j] = h;
      WpLo[(size_t)tid * 8 + j] = f2bf(v - bf2f(h));
    }
  } else if (tid < 2048 + 9216){
    int idx = tid - 2048;
    int lane = idx & 63, kc = (idx >> 6) & 3, t2 = idx >> 8;  // t2 = m*12+h
    int h = t2 % 12, m = t2 / 12;
    const float* W = (m == 0) ? Wq : (m == 1) ? Wk : Wv;
    int g = lane >> 4, l15 = lane & 15;
    #pragma unroll
    for (int j = 0; j < 8; ++j){
      int k = kc * 32 + g * 8 + j;
      float v = (l15 < 10) ? W[k * 120 + h * 10 + l15] : 0.f;
      QHi[(size_t)idx * 8 + j] = f2bf(v);
    }
  } else if (tid < 2048 + 9216 + 576){
    int idx = tid - (2048 + 9216);
    int m = idx / 192, rest = idx % 192;
    int h = rest / 16, d = rest % 16;
    const float* B = (m == 0) ? bq : (m == 1) ? bk : bv;
    biasPad[idx] = (d < 10) ? B[h * 10 + d] : 0.f;
  }
}

// ---------------- x0 = emb[ids] (f32 -> bf16) ----------------
__global__ void k_gather(const int* __restrict__ ids, const float* __restrict__ emb,
                         uint16_t* __restrict__ x){
  int tid = blockIdx.x * 256 + threadIdx.x;          // T*N*16
  int row = tid >> 4, c8 = tid & 15;
  int id = ids[row];
  const float* er = emb + (size_t)id * DD + c8 * 8;
  float4 a = *(const float4*)er;
  float4 b = *(const float4*)(er + 4);
  union { uint32_t u[4]; bvec8 v; } o;
  o.u[0] = cvtpk(a.x, a.y);
  o.u[1] = cvtpk(a.z, a.w);
  o.u[2] = cvtpk(b.x, b.y);
  o.u[3] = cvtpk(b.z, b.w);
  *(bvec8*)(x + (size_t)row * DD + c8 * 8) = o.v;
}

// ---------------- fused propagate: n_hat = x + scatter; out = n_hat@Wp + bp ----------------
__global__ __launch_bounds__(256, 4) void k_prop(const uint16_t* __restrict__ xin,
    uint16_t* __restrict__ xout, const int* __restrict__ cnt, const int* __restrict__ csrS,
    const float* __restrict__ csrW, const uint16_t* __restrict__ WHi,
    const uint16_t* __restrict__ WLo, const float* __restrict__ bp, int topt){
  __shared__ uint16_t lds[64 * 136];
  int vb = blockIdx.x;
  int b = ((vb & 7) << 8) | (vb >> 3);                // XCD swizzle: one t handled on one XCD
  int t = b >> 5, n0 = (b & 31) << 6;
  int tid = threadIdx.x, w = tid >> 6, lane = tid & 63, g = lane >> 4, l15 = lane & 15;
  const uint16_t* xt = xin + (size_t)t * NN * DD;
  int baseRow = t * NN + n0 + w * 16;
  int myc = (lane < 16) ? cnt[baseRow + lane] : 0;
  // phase 1: n_hat rows -> LDS (bf16); 8-wide predicated gather pipeline per row
  #pragma unroll 2
  for (int i = 0; i < 16; ++i){
    int r = w * 16 + i;
    int n = n0 + r;
    int rowg = baseRow + i;
    uint32_t u = *(const uint32_t*)(xt + (size_t)n * DD + (lane << 1));
    int c = __shfl(myc, i);
    const int* ss = csrS + (size_t)rowg * CAP;
    const float* ww = csrW + (size_t)rowg * CAP;
    int4 sA = *(const int4*)ss;
    int4 sB = *(const int4*)(ss + 4);
    float4 wA = *(const float4*)ww;
    float4 wB = *(const float4*)(ww + 4);
    int sj[8] = {sA.x, sA.y, sA.z, sA.w, sB.x, sB.y, sB.z, sB.w};
    float wj[8] = {wA.x, wA.y, wA.z, wA.w, wB.x, wB.y, wB.z, wB.w};
    uint32_t xs[8];
    float wf[8];
    #pragma unroll
    for (int j = 0; j < 8; ++j){
      int s = (j < c) ? sj[j] : n;         // clamp garbage indices, zero the weight
      wf[j] = (j < c) ? wj[j] : 0.f;
      xs[j] = *(const uint32_t*)(xt + (size_t)s * DD + (lane << 1));
    }
    float a0 = bf2f((uint16_t)(u & 0xffffu));
    float a1 = bf2f((uint16_t)(u >> 16));
    #pragma unroll
    for (int j = 0; j < 8; ++j){
      a0 = fmaf(wf[j], bf2f((uint16_t)(xs[j] & 0xffffu)), a0);
      a1 = fmaf(wf[j], bf2f((uint16_t)(xs[j] >> 16)), a1);
    }
    if (c > 8){                             // rare tail
      for (int j = 8; j < c; ++j){
        int s = ss[j];
        float wt = ww[j];
        uint32_t us = *(const uint32_t*)(xt + (size_t)s * DD + (lane << 1));
        a0 = fmaf(wt, bf2f((uint16_t)(us & 0xffffu)), a0);
        a1 = fmaf(wt, bf2f((uint16_t)(us >> 16)), a1);
      }
    }
    *(uint32_t*)&lds[r * 136 + (lane << 1)] = cvtpk(a0, a1);
  }
  __syncthreads();
  // phase 2: GEMM [64x128] @ [128x128], wave w -> row-tile w
  bvec8 afr[4];
  int arow = w * 16 + l15;
  #pragma unroll
  for (int kc = 0; kc < 4; ++kc)
    afr[kc] = *(const bvec8*)&lds[arow * 136 + kc * 32 + g * 8];
  fvec4 acc[8];
  #pragma unroll
  for (int i = 0; i < 8; ++i) acc[i] = fvec4{0.f, 0.f, 0.f, 0.f};
  #pragma unroll
  for (int kc = 0; kc < 4; ++kc){
    #pragma unroll
    for (int ct = 0; ct < 8; ++ct){
      size_t base = ((size_t)(ct * 4 + kc) * 64 + lane) * 8;
      acc[ct] = mfma16(afr[kc], *(const bvec8*)&WHi[base], acc[ct]);
      acc[ct] = mfma16(afr[kc], *(const bvec8*)&WLo[base], acc[ct]);
    }
  }
  __syncthreads();
  // epilogue: C + bias -> bf16 back into LDS
  #pragma unroll
  for (int ct = 0; ct < 8; ++ct){
    int col = ct * 16 + l15;
    float bias = bp[col];
    uint32_t c01 = cvtpk(acc[ct][0] + bias, acc[ct][1] + bias);
    uint32_t c23 = cvtpk(acc[ct][2] + bias, acc[ct][3] + bias);
    int r = w * 16 + g * 4;
    lds[(r + 0) * 136 + col] = (uint16_t)c01;
    lds[(r + 1) * 136 + col] = (uint16_t)(c01 >> 16);
    lds[(r + 2) * 136 + col] = (uint16_t)c23;
    lds[(r + 3) * 136 + col] = (uint16_t)(c23 >> 16);
  }
  __syncthreads();
  // store (topt: last round writes [n][t][d] for attention)
  #pragma unroll
  for (int p = 0; p < 4; ++p){
    int chunk = p * 256 + tid, r = chunk >> 4, c8 = chunk & 15;
    bvec8 v = *(const bvec8*)&lds[r * 136 + c8 * 8];
    size_t dstoff;
    if (topt == 0) dstoff = ((size_t)t * NN + n0 + r) * DD + c8 * 8;
    else           dstoff = (((size_t)(n0 + r)) * TT + t) * DD + c8 * 8;
    *(bvec8*)(xout + dstoff) = v;
  }
}

// ---------------- fused QKV + attention + partial mean ----------------
// Head-per-wave: wave w handles heads {w, 4+w, 8+w}. seq staged in shared
// LDS once (single __syncthreads); everything after is wave-private.
// Register discipline: A-fragments (16 bvec8) loaded once per pass, QKV
// computed per-matrix with acc[4] (16 regs) to avoid spills.
__global__ __launch_bounds__(256, 3) void k_attn(const uint16_t* __restrict__ x3,
    const uint16_t* __restrict__ QHi, const float* __restrict__ biasPad,
    float* __restrict__ partials){
  __shared__ uint16_t seq[64 * 136];                  // 17408 B, read-only after stage
  __shared__ uint16_t ldsA[4][4480];                  // 35840 B wave-private
  int n = blockIdx.x;
  int tid = threadIdx.x, w = tid >> 6, lane = tid & 63, g = lane >> 4, l15 = lane & 15;
  uint16_t* Kw = &ldsA[w][0];
  uint16_t* Qw = &ldsA[w][1152];
  uint16_t* Vt = &ldsA[w][2304];
  uint16_t* Pw = &ldsA[w][3392];
  const uint16_t* xr = x3 + (size_t)n * TT * DD;
  #pragma unroll
  for (int p4 = 0; p4 < 4; ++p4){
    int chunk = p4 * 256 + tid, r = chunk >> 4, c8 = chunk & 15;
    *(bvec8*)&seq[r * 136 + c8 * 8] = *(const bvec8*)&xr[r * 128 + c8 * 8];
  }
  __syncthreads();                                    // the only barrier
  const int r7 = l15 & 7;
  const float CSC = 0.31622776601683794f * 1.4426950408889634f;  // (1/sqrt(10))*log2(e)

  for (int pass = 0; pass < 3; ++pass){
    int h = pass * 4 + w;
    // A-fragments for all 64 t-rows, once per pass (64 VGPR, dead after QKV)
    bvec8 afr[16];
    #pragma unroll
    for (int ti = 0; ti < 4; ++ti)
      #pragma unroll
      for (int kc = 0; kc < 4; ++kc)
        afr[ti * 4 + kc] = *(const bvec8*)&seq[(ti * 16 + l15) * 136 + kc * 32 + g * 8];
    // ---- QKV for head h, one matrix at a time (acc[4] only) ----
    #pragma unroll
    for (int m = 0; m < 3; ++m){
      fvec4 acc[4];
      #pragma unroll
      for (int i = 0; i < 4; ++i) acc[i] = fvec4{0.f, 0.f, 0.f, 0.f};
      #pragma unroll
      for (int kc = 0; kc < 4; ++kc){
        bvec8 B = *(const bvec8*)&QHi[((size_t)((m * 12 + h) * 4 + kc) * 64 + lane) * 8];
        #pragma unroll
        for (int ti = 0; ti < 4; ++ti)
          acc[ti] = mfma16(afr[ti * 4 + kc], B, acc[ti]);
      }
      float bias = biasPad[(m * 12 + h) * 16 + l15];
      #pragma unroll
      for (int ti = 0; ti < 4; ++ti){
        uint32_t p01 = cvtpk(acc[ti][0] + bias, acc[ti][1] + bias);
        uint32_t p23 = cvtpk(acc[ti][2] + bias, acc[ti][3] + bias);
        int rb = ti * 16 + g * 4;
        if (m == 0){
          Qw[(rb + 0) * 18 + l15] = (uint16_t)p01;
          Qw[(rb + 1) * 18 + l15] = (uint16_t)(p01 >> 16);
          Qw[(rb + 2) * 18 + l15] = (uint16_t)p23;
          Qw[(rb + 3) * 18 + l15] = (uint16_t)(p23 >> 16);
        } else if (m == 1){
          Kw[(rb + 0) * 18 + l15] = (uint16_t)p01;
          Kw[(rb + 1) * 18 + l15] = (uint16_t)(p01 >> 16);
          Kw[(rb + 2) * 18 + l15] = (uint16_t)p23;
          Kw[(rb + 3) * 18 + l15] = (uint16_t)(p23 >> 16);
        } else {
          int e = ti * 16 + g * 4;
          int ch = (e >> 3) ^ r7;
          uint2 val; val.x = p01; val.y = p23;
          *(uint2*)&Vt[l15 * 68 + (ch << 3) + (e & 7)] = val;   // Vt[d][s] swizzled
        }
      }
    }
    // ---- attention for head h; S^T via mfma(K,Q); softmax s-axis in-lane ----
    bvec8 zf = bvec8{};
    bvec8 kfr[4];
    #pragma unroll
    for (int si = 0; si < 4; ++si)
      kfr[si] = (g < 2) ? *(const bvec8*)&Kw[(si * 16 + l15) * 18 + g * 8] : zf;
    float csum = 0.f;
    #pragma unroll
    for (int ti = 0; ti < 4; ++ti){
      bvec8 qf = (g < 2) ? *(const bvec8*)&Qw[(ti * 16 + l15) * 18 + g * 8] : zf;
      fvec4 p[4];
      #pragma unroll
      for (int si = 0; si < 4; ++si)
        p[si] = mfma16(kfr[si], qf, fvec4{0.f, 0.f, 0.f, 0.f});
      // exp without rowmax: scores O(0.1); softmax shift-invariant -> exact
      float s = 0.f;
      #pragma unroll
      for (int si = 0; si < 4; ++si)
        #pragma unroll
        for (int rg = 0; rg < 4; ++rg){
          float pv = exp2f(p[si][rg] * CSC);
          p[si][rg] = pv;
          s += pv;
        }
      s += __shfl_xor(s, 16);
      s += __shfl_xor(s, 32);
      float rinv = __builtin_amdgcn_rcpf(s);
      // P^T tile -> Pw[t-local][s] (b64 packed, swizzled), normalized
      #pragma unroll
      for (int si = 0; si < 4; ++si){
        uint32_t a = cvtpk(p[si][0] * rinv, p[si][1] * rinv);
        uint32_t b = cvtpk(p[si][2] * rinv, p[si][3] * rinv);
        int e = si * 16 + g * 4;
        int ch = (e >> 3) ^ r7;
        uint2 val; val.x = a; val.y = b;
        *(uint2*)&Pw[l15 * 68 + (ch << 3) + (e & 7)] = val;
      }
      // PV: O[t-local][d=l15], accumulate column sums
      fvec4 o = fvec4{0.f, 0.f, 0.f, 0.f};
      #pragma unroll
      for (int kc = 0; kc < 2; ++kc){
        int ch = ((kc * 32 + g * 8) >> 3) ^ r7;
        bvec8 pa = *(const bvec8*)&Pw[l15 * 68 + (ch << 3)];
        bvec8 vb = *(const bvec8*)&Vt[l15 * 68 + (ch << 3)];
        o = mfma16(pa, vb, o);
      }
      csum += o[0] + o[1] + o[2] + o[3];
    }
    csum += __shfl_xor(csum, 16);
    csum += __shfl_xor(csum, 32);
    if (g == 0 && l15 < 10)
      partials[(size_t)n * 120 + h * 10 + l15] = csum;
  }
}

// ---------------- deterministic reductions ----------------
__global__ void k_reduce(const float* __restrict__ partials, float* __restrict__ agg){
  __shared__ float red[256];
  int c = blockIdx.x, tid = threadIdx.x;
  float s = 0.f;
  for (int b = tid; b < NN; b += 256) s += partials[(size_t)b * 120 + c];
  red[tid] = s;
  __syncthreads();
  for (int st = 128; st > 0; st >>= 1){
    if (tid < st) red[tid] += red[tid + st];
    __syncthreads();
  }
  if (tid == 0) agg[c] = red[0] * (1.0f / (float)(NN * TT));
}

__global__ void k_final(const float* __restrict__ agg, const float* __restrict__ Wo,
                        const float* __restrict__ bo, float* __restrict__ out){
  __shared__ float r0[128], r1[128];
  int j = threadIdx.x;
  float a = (j < 120) ? agg[j] : 0.f;
  r0[j] = (j < 120) ? a * Wo[2 * j] : 0.f;
  r1[j] = (j < 120) ? a * Wo[2 * j + 1] : 0.f;
  __syncthreads();
  for (int st = 64; st > 0; st >>= 1){
    if (j < st){ r0[j] += r0[j + st]; r1[j] += r1[j + st]; }
    __syncthreads();
  }
  if (j == 0){ out[0] = r0[0] + bo[0]; out[1] = r1[0] + bo[1]; }
}

extern "C" void kernel_launch(void* const* d_in, const int* in_sizes, int n_in,
                              void* d_out, int out_size, void* d_ws, size_t ws_size,
                              hipStream_t stream){
  const int*   node_ids = (const int*)d_in[0];
  const int*   srcA     = (const int*)d_in[1];
  const int*   dstA     = (const int*)d_in[2];
  const float* ew       = (const float*)d_in[3];
  const float* emb      = (const float*)d_in[4];
  const float* Wp       = (const float*)d_in[5];
  const float* bp       = (const float*)d_in[6];
  const float* Wq       = (const float*)d_in[7];
  const float* bq       = (const float*)d_in[8];
  const float* Wk       = (const float*)d_in[9];
  const float* bk       = (const float*)d_in[10];
  const float* Wv       = (const float*)d_in[11];
  const float* bv       = (const float*)d_in[12];
  const float* Wo       = (const float*)d_in[13];
  const float* bo       = (const float*)d_in[14];

  char* p = (char*)d_ws;
  auto alloc = [&](size_t bytes) -> char* {
    char* r = p; p += (bytes + 255) & ~(size_t)255; return r;
  };
  uint16_t* xA    = (uint16_t*)alloc((size_t)TT * NN * DD * 2);
  uint16_t* xB    = (uint16_t*)alloc((size_t)TT * NN * DD * 2);
  int*      cnt   = (int*)alloc((size_t)TT * NN * 4);
  int*      es    = (int*)alloc((size_t)TT * NN * CAP * 4);
  float*    wcsr  = (float*)alloc((size_t)TT * NN * CAP * 4);
  uint16_t* WpHi  = (uint16_t*)alloc(2048 * 8 * 2);
  uint16_t* WpLo  = (uint16_t*)alloc(2048 * 8 * 2);
  uint16_t* QHi   = (uint16_t*)alloc(9216 * 8 * 2);
  float*    biasP = (float*)alloc(576 * 4);
  float*    parts = (float*)alloc((size_t)NN * 120 * 4);
  float*    agg   = (float*)alloc(120 * 4);

  hipMemsetAsync(cnt, 0, (size_t)TT * NN * 4, stream);
  k_fill<<<TT * EE / 256, 256, 0, stream>>>(dstA, cnt, es);
  k_sortconv<<<TT * NN / 256, 256, 0, stream>>>(cnt, es, wcsr, srcA, ew);
  k_prep<<<47, 256, 0, stream>>>(Wp, Wq, Wk, Wv, bq, bk, bv, WpHi, WpLo, QHi, biasP);
  k_gather<<<TT * NN * 16 / 256, 256, 0, stream>>>(node_ids, emb, xA);
  k_prop<<<2048, 256, 0, stream>>>(xA, xB, cnt, es, wcsr, WpHi, WpLo, bp, 0);
  k_prop<<<2048, 256, 0, stream>>>(xB, xA, cnt, es, wcsr, WpHi, WpLo, bp, 0);
  k_prop<<<2048, 256, 0, stream>>>(xA, xB, cnt, es, wcsr, WpHi, WpLo, bp, 1);
  k_attn<<<NN, 256, 0, stream>>>(xB, QHi, biasP, parts);
  k_reduce<<<120, 256, 0, stream>>>(parts, agg);
  k_final<<<1, 128, 0, stream>>>(agg, Wo, bo, (float*)d_out);
}

// Round 7
// 290.348 us; speedup vs baseline: 1.3145x; 1.1001x over previous
//
#include <hip/hip_runtime.h>
#include <stdint.h>

#define TT 64
#define NN 2048
#define EE 8192
#define DD 128
#define CAP 32

typedef __attribute__((ext_vector_type(8))) short bvec8;
typedef __attribute__((ext_vector_type(4))) float fvec4;

__device__ __forceinline__ float bf2f(uint16_t u){
  union { uint32_t i; float f; } v; v.i = ((uint32_t)u) << 16; return v.f;
}
__device__ __forceinline__ uint16_t f2bf(float f){
  union { float f; uint32_t i; } v; v.f = f;
  uint32_t r = v.i + 0x7fffu + ((v.i >> 16) & 1u);
  return (uint16_t)(r >> 16);
}
// packed f32x2 -> bf16x2 (RNE), single VALU instr
__device__ __forceinline__ uint32_t cvtpk(float lo, float hi){
  uint32_t r;
  asm("v_cvt_pk_bf16_f32 %0, %1, %2" : "=v"(r) : "v"(lo), "v"(hi));
  return r;
}
__device__ __forceinline__ fvec4 mfma16(bvec8 a, bvec8 b, fvec4 c){
  return __builtin_amdgcn_mfma_f32_16x16x32_bf16(a, b, c, 0, 0, 0);
}
// 4 payload values in k-slots (g*8+0..3), zeros in slots 4..7. Both operands
// of a product use the same padding -> zero slots contribute exactly 0.
__device__ __forceinline__ bvec8 pack8z(float a, float b, float c, float d){
  union { uint32_t u[4]; bvec8 v; } r;
  r.u[0] = cvtpk(a, b);
  r.u[1] = cvtpk(c, d);
  r.u[2] = 0u;
  r.u[3] = 0u;
  return r.v;
}

// ---------------- CSR build (deterministic) ----------------
// esw layout: per row, CAP interleaved (key/src, weight) int pairs.
__global__ void k_fill(const int* __restrict__ dst, int* __restrict__ cnt, int* __restrict__ esw){
  int tid = blockIdx.x * 256 + threadIdx.x;          // T*E threads
  int t = tid >> 13, e = tid & (EE - 1);
  int d = dst[tid];
  int row = t * NN + d;
  int pos = atomicAdd(&cnt[row], 1);
  if (pos < CAP) esw[(size_t)row * 2 * CAP + 2 * pos] = e;
}

// in-place: sort edge ids (stride-2 keys, deterministic), then convert to (src, weight)
__global__ void k_sortconv(int* __restrict__ cnt, int* __restrict__ esw,
                           const int* __restrict__ srcA, const float* __restrict__ ewA){
  int row = blockIdx.x * 256 + threadIdx.x;          // T*N threads
  if (row >= TT * NN) return;
  int t = row >> 11;
  int c = cnt[row]; if (c > CAP) c = CAP;
  cnt[row] = c;
  int* p = esw + (size_t)row * 2 * CAP;
  for (int i = 0; i < c; ++i){                        // selection sort ascending
    int mi = i, mv = p[2 * i];
    for (int j = i + 1; j < c; ++j){ int vj = p[2 * j]; if (vj < mv){ mv = vj; mi = j; } }
    if (mi != i){ p[2 * mi] = p[2 * i]; p[2 * i] = mv; }
  }
  const int* srcT = srcA + (size_t)t * EE;
  const float* ewT = ewA + (size_t)t * EE;
  for (int i = 0; i < c; ++i){
    int e = p[2 * i];
    p[2 * i]     = srcT[e];
    p[2 * i + 1] = __float_as_int(ewT[e]);
  }
}

// ---------------- weight packing (Wp hi/lo bf16 split; QKV hi-only) ----------------
__global__ void k_prep(const float* __restrict__ Wp, const float* __restrict__ Wq,
                       const float* __restrict__ Wk, const float* __restrict__ Wv,
                       const float* __restrict__ bq, const float* __restrict__ bk,
                       const float* __restrict__ bv,
                       uint16_t* __restrict__ WpHi, uint16_t* __restrict__ WpLo,
                       uint16_t* __restrict__ QHi, float* __restrict__ biasPad){
  int tid = blockIdx.x * 256 + threadIdx.x;
  if (tid < 2048){
    int lane = tid & 63, kc = (tid >> 6) & 3, ct = tid >> 8;
    int g = lane >> 4, l15 = lane & 15;
    #pragma unroll
    for (int j = 0; j < 8; ++j){
      int k = kc * 32 + g * 8 + j;
      int col = ct * 16 + l15;
      float v = Wp[k * DD + col];
      uint16_t h = f2bf(v);
      WpHi[(size_t)tid * 8 + j] = h;
      WpLo[(size_t)tid * 8 + j] = f2bf(v - bf2f(h));
    }
  } else if (tid < 2048 + 9216){
    int idx = tid - 2048;
    int lane = idx & 63, kc = (idx >> 6) & 3, t2 = idx >> 8;  // t2 = m*12+h
    int h = t2 % 12, m = t2 / 12;
    const float* W = (m == 0) ? Wq : (m == 1) ? Wk : Wv;
    int g = lane >> 4, l15 = lane & 15;
    #pragma unroll
    for (int j = 0; j < 8; ++j){
      int k = kc * 32 + g * 8 + j;
      float v = (l15 < 10) ? W[k * 120 + h * 10 + l15] : 0.f;
      QHi[(size_t)idx * 8 + j] = f2bf(v);
    }
  } else if (tid < 2048 + 9216 + 576){
    int idx = tid - (2048 + 9216);
    int m = idx / 192, rest = idx % 192;
    int h = rest / 16, d = rest % 16;
    const float* B = (m == 0) ? bq : (m == 1) ? bk : bv;
    biasPad[idx] = (d < 10) ? B[h * 10 + d] : 0.f;
  }
}

// ---------------- x0 = emb[ids] (f32 -> bf16) ----------------
__global__ void k_gather(const int* __restrict__ ids, const float* __restrict__ emb,
                         uint16_t* __restrict__ x){
  int tid = blockIdx.x * 256 + threadIdx.x;          // T*N*16
  int row = tid >> 4, c8 = tid & 15;
  int id = ids[row];
  const float* er = emb + (size_t)id * DD + c8 * 8;
  float4 a = *(const float4*)er;
  float4 b = *(const float4*)(er + 4);
  union { uint32_t u[4]; bvec8 v; } o;
  o.u[0] = cvtpk(a.x, a.y);
  o.u[1] = cvtpk(a.z, a.w);
  o.u[2] = cvtpk(b.x, b.y);
  o.u[3] = cvtpk(b.z, b.w);
  *(bvec8*)(x + (size_t)row * DD + c8 * 8) = o.v;
}

// ---------------- fused propagate: n_hat = x + scatter; out = n_hat@Wp + bp ----------------
__global__ __launch_bounds__(256, 4) void k_prop(const uint16_t* __restrict__ xin,
    uint16_t* __restrict__ xout, const int* __restrict__ cnt, const int* __restrict__ esw,
    const uint16_t* __restrict__ WHi, const uint16_t* __restrict__ WLo,
    const float* __restrict__ bp, int topt){
  __shared__ uint16_t lds[64 * 136];
  int vb = blockIdx.x;
  int b = ((vb & 7) << 8) | (vb >> 3);                // XCD swizzle: one t handled on one XCD
  int t = b >> 5, n0 = (b & 31) << 6;
  int tid = threadIdx.x, w = tid >> 6, lane = tid & 63, g = lane >> 4, l15 = lane & 15;
  const uint16_t* xt = xin + (size_t)t * NN * DD;
  int baseRow = t * NN + n0 + w * 16;
  int myc = (lane < 16) ? cnt[baseRow + lane] : 0;
  // phase 1: n_hat rows -> LDS (bf16); flat 8-wide predicated gather (r4-proven shape)
  #pragma unroll 2
  for (int i = 0; i < 16; ++i){
    int r = w * 16 + i;
    int n = n0 + r;
    int rowg = baseRow + i;
    uint32_t u = *(const uint32_t*)(xt + (size_t)n * DD + (lane << 1));
    int c = __shfl(myc, i);                           // wave-uniform
    const int4* ep = (const int4*)(esw + (size_t)rowg * 2 * CAP);
    int4 q0 = ep[0], q1 = ep[1], q2 = ep[2], q3 = ep[3];
    int sj[8]   = {q0.x, q0.z, q1.x, q1.z, q2.x, q2.z, q3.x, q3.z};
    float wj[8] = {__int_as_float(q0.y), __int_as_float(q0.w),
                   __int_as_float(q1.y), __int_as_float(q1.w),
                   __int_as_float(q2.y), __int_as_float(q2.w),
                   __int_as_float(q3.y), __int_as_float(q3.w)};
    uint32_t xs[8];
    float wf[8];
    #pragma unroll
    for (int j = 0; j < 8; ++j){
      int s = (j < c) ? sj[j] : n;                    // clamp garbage idx, zero weight
      wf[j] = (j < c) ? wj[j] : 0.f;
      xs[j] = *(const uint32_t*)(xt + (size_t)s * DD + (lane << 1));
    }
    float a0 = bf2f((uint16_t)(u & 0xffffu));
    float a1 = bf2f((uint16_t)(u >> 16));
    #pragma unroll
    for (int j = 0; j < 8; ++j){
      a0 = fmaf(wf[j], bf2f((uint16_t)(xs[j] & 0xffffu)), a0);
      a1 = fmaf(wf[j], bf2f((uint16_t)(xs[j] >> 16)), a1);
    }
    if (c > 8){                                       // rare tail (P ~ 2%)
      for (int j = 8; j < c; ++j){
        int s = esw[(size_t)rowg * 2 * CAP + 2 * j];
        float wt = __int_as_float(esw[(size_t)rowg * 2 * CAP + 2 * j + 1]);
        uint32_t us = *(const uint32_t*)(xt + (size_t)s * DD + (lane << 1));
        a0 = fmaf(wt, bf2f((uint16_t)(us & 0xffffu)), a0);
        a1 = fmaf(wt, bf2f((uint16_t)(us >> 16)), a1);
      }
    }
    *(uint32_t*)&lds[r * 136 + (lane << 1)] = cvtpk(a0, a1);
  }
  __syncthreads();
  // phase 2: GEMM [64x128] @ [128x128], wave w -> row-tile w
  bvec8 afr[4];
  int arow = w * 16 + l15;
  #pragma unroll
  for (int kc = 0; kc < 4; ++kc)
    afr[kc] = *(const bvec8*)&lds[arow * 136 + kc * 32 + g * 8];
  fvec4 acc[8];
  #pragma unroll
  for (int i = 0; i < 8; ++i) acc[i] = fvec4{0.f, 0.f, 0.f, 0.f};
  #pragma unroll
  for (int kc = 0; kc < 4; ++kc){
    #pragma unroll
    for (int ct = 0; ct < 8; ++ct){
      size_t base = ((size_t)(ct * 4 + kc) * 64 + lane) * 8;
      acc[ct] = mfma16(afr[kc], *(const bvec8*)&WHi[base], acc[ct]);
      acc[ct] = mfma16(afr[kc], *(const bvec8*)&WLo[base], acc[ct]);
    }
  }
  __syncthreads();
  // epilogue: C + bias -> bf16 back into LDS
  #pragma unroll
  for (int ct = 0; ct < 8; ++ct){
    int col = ct * 16 + l15;
    float bias = bp[col];
    uint32_t c01 = cvtpk(acc[ct][0] + bias, acc[ct][1] + bias);
    uint32_t c23 = cvtpk(acc[ct][2] + bias, acc[ct][3] + bias);
    int r = w * 16 + g * 4;
    lds[(r + 0) * 136 + col] = (uint16_t)c01;
    lds[(r + 1) * 136 + col] = (uint16_t)(c01 >> 16);
    lds[(r + 2) * 136 + col] = (uint16_t)c23;
    lds[(r + 3) * 136 + col] = (uint16_t)(c23 >> 16);
  }
  __syncthreads();
  // store (topt: last round writes [n][t][d] for attention)
  #pragma unroll
  for (int p = 0; p < 4; ++p){
    int chunk = p * 256 + tid, r = chunk >> 4, c8 = chunk & 15;
    bvec8 v = *(const bvec8*)&lds[r * 136 + c8 * 8];
    size_t dstoff;
    if (topt == 0) dstoff = ((size_t)t * NN + n0 + r) * DD + c8 * 8;
    else           dstoff = (((size_t)(n0 + r)) * TT + t) * DD + c8 * 8;
    *(bvec8*)(xout + dstoff) = v;
  }
}

// ---------------- fused QKV + attention + partial mean ----------------
// Head-per-wave; register-resident attention using ONLY the verified
// 16x16x32 MFMA. Zero-padded K=32 trick: S/PV operands carry their 4
// payload values in k-slots g*8+0..3 and zeros in slots 4..7 (both sides
// padded identically -> zero slots contribute exactly 0).
//  Q^T,K^T = mfma16(W, X)  -> lane=t(l&15), regs d=g*4+rg
//  S       = mfma16(kf8, qf8) -> lane=t, regs s=g*4+rg
//  V       = mfma16(X, Wv) -> lane=d, regs t(=s)=g*4+rg
//  O       = mfma16(pf8, vf8) -> lane=d, regs t
// One barrier total (seq stage); no LDS in the per-pass loops.
__global__ __launch_bounds__(256, 3) void k_attn(const uint16_t* __restrict__ x3,
    const uint16_t* __restrict__ QHi, const float* __restrict__ biasPad,
    float* __restrict__ partials){
  __shared__ uint16_t seq[64 * 136];                  // 17408 B
  int n = blockIdx.x;
  int tid = threadIdx.x, w = tid >> 6, lane = tid & 63, g = lane >> 4, l15 = lane & 15;
  const uint16_t* xr = x3 + (size_t)n * TT * DD;
  #pragma unroll
  for (int p4 = 0; p4 < 4; ++p4){
    int chunk = p4 * 256 + tid, r = chunk >> 4, c8 = chunk & 15;
    *(bvec8*)&seq[r * 136 + c8 * 8] = *(const bvec8*)&xr[r * 128 + c8 * 8];
  }
  __syncthreads();                                    // the only barrier

  const float CSC = 0.31622776601683794f * 1.4426950408889634f;  // (1/sqrt(10))*log2(e)

  for (int pass = 0; pass < 3; ++pass){
    int h = pass * 4 + w;
    bvec8 qf8[4], kf8[4], vf8[4];
    #pragma unroll
    for (int m = 0; m < 3; ++m){
      fvec4 acc[4];
      #pragma unroll
      for (int i = 0; i < 4; ++i) acc[i] = fvec4{0.f, 0.f, 0.f, 0.f};
      #pragma unroll
      for (int kc = 0; kc < 4; ++kc){
        bvec8 B = *(const bvec8*)&QHi[((size_t)((m * 12 + h) * 4 + kc) * 64 + lane) * 8];
        #pragma unroll
        for (int tb = 0; tb < 4; ++tb){
          bvec8 a = *(const bvec8*)&seq[(tb * 16 + l15) * 136 + kc * 32 + g * 8];
          if (m == 2) acc[tb] = mfma16(a, B, acc[tb]);  // V: lane=d, regs=t
          else        acc[tb] = mfma16(B, a, acc[tb]);  // Q,K: lane=t, regs=d
        }
      }
      if (m == 2){
        float bias = biasPad[(2 * 12 + h) * 16 + l15];  // per-d bias (lane=d)
        #pragma unroll
        for (int tb = 0; tb < 4; ++tb)
          vf8[tb] = pack8z(acc[tb][0] + bias, acc[tb][1] + bias,
                           acc[tb][2] + bias, acc[tb][3] + bias);
      } else {
        float4 b4 = *(const float4*)&biasPad[(m * 12 + h) * 16 + g * 4];  // per-d (regs=d)
        #pragma unroll
        for (int tb = 0; tb < 4; ++tb){
          bvec8 f = pack8z(acc[tb][0] + b4.x, acc[tb][1] + b4.y,
                           acc[tb][2] + b4.z, acc[tb][3] + b4.w);
          if (m == 0) qf8[tb] = f; else kf8[tb] = f;
        }
      }
    }
    // ---- attention, all in registers ----
    float csum = 0.f;
    #pragma unroll
    for (int tb = 0; tb < 4; ++tb){
      fvec4 p[4];
      #pragma unroll
      for (int sb = 0; sb < 4; ++sb)
        p[sb] = mfma16(kf8[sb], qf8[tb], fvec4{0.f, 0.f, 0.f, 0.f});
      // exp without rowmax: scores O(0.1); softmax shift-invariant -> exact.
      // fmin clamp is a no-op for valid data; keeps corruption finite/diagnosable.
      float s = 0.f;
      #pragma unroll
      for (int sb = 0; sb < 4; ++sb)
        #pragma unroll
        for (int rg = 0; rg < 4; ++rg){
          float pv = exp2f(fminf(p[sb][rg] * CSC, 80.0f));
          p[sb][rg] = pv;
          s += pv;
        }
      s += __shfl_xor(s, 16);
      s += __shfl_xor(s, 32);
      float rinv = __builtin_amdgcn_rcpf(s);
      fvec4 o = fvec4{0.f, 0.f, 0.f, 0.f};
      #pragma unroll
      for (int sb = 0; sb < 4; ++sb){
        bvec8 pf = pack8z(p[sb][0] * rinv, p[sb][1] * rinv,
                          p[sb][2] * rinv, p[sb][3] * rinv);
        o = mfma16(pf, vf8[sb], o);
      }
      csum += o[0] + o[1] + o[2] + o[3];
    }
    csum += __shfl_xor(csum, 16);
    csum += __shfl_xor(csum, 32);
    if (g == 0 && l15 < 10)
      partials[(size_t)n * 120 + h * 10 + l15] = csum;
  }
}

// ---------------- deterministic reductions ----------------
__global__ void k_reduce(const float* __restrict__ partials, float* __restrict__ agg){
  __shared__ float red[256];
  int c = blockIdx.x, tid = threadIdx.x;
  float s = 0.f;
  for (int b = tid; b < NN; b += 256) s += partials[(size_t)b * 120 + c];
  red[tid] = s;
  __syncthreads();
  for (int st = 128; st > 0; st >>= 1){
    if (tid < st) red[tid] += red[tid + st];
    __syncthreads();
  }
  if (tid == 0) agg[c] = red[0] * (1.0f / (float)(NN * TT));
}

__global__ void k_final(const float* __restrict__ agg, const float* __restrict__ Wo,
                        const float* __restrict__ bo, float* __restrict__ out){
  __shared__ float r0[128], r1[128];
  int j = threadIdx.x;
  float a = (j < 120) ? agg[j] : 0.f;
  r0[j] = (j < 120) ? a * Wo[2 * j] : 0.f;
  r1[j] = (j < 120) ? a * Wo[2 * j + 1] : 0.f;
  __syncthreads();
  for (int st = 64; st > 0; st >>= 1){
    if (j < st){ r0[j] += r0[j + st]; r1[j] += r1[j + st]; }
    __syncthreads();
  }
  if (j == 0){ out[0] = r0[0] + bo[0]; out[1] = r1[0] + bo[1]; }
}

extern "C" void kernel_launch(void* const* d_in, const int* in_sizes, int n_in,
                              void* d_out, int out_size, void* d_ws, size_t ws_size,
                              hipStream_t stream){
  const int*   node_ids = (const int*)d_in[0];
  const int*   srcA     = (const int*)d_in[1];
  const int*   dstA     = (const int*)d_in[2];
  const float* ew       = (const float*)d_in[3];
  const float* emb      = (const float*)d_in[4];
  const float* Wp       = (const float*)d_in[5];
  const float* bp       = (const float*)d_in[6];
  const float* Wq       = (const float*)d_in[7];
  const float* bq       = (const float*)d_in[8];
  const float* Wk       = (const float*)d_in[9];
  const float* bk       = (const float*)d_in[10];
  const float* Wv       = (const float*)d_in[11];
  const float* bv       = (const float*)d_in[12];
  const float* Wo       = (const float*)d_in[13];
  const float* bo       = (const float*)d_in[14];

  char* p = (char*)d_ws;
  auto alloc = [&](size_t bytes) -> char* {
    char* r = p; p += (bytes + 255) & ~(size_t)255; return r;
  };
  // Total ~102.4 MB (round-4-proven footprint)
  uint16_t* xA    = (uint16_t*)alloc((size_t)TT * NN * DD * 2);
  uint16_t* xB    = (uint16_t*)alloc((size_t)TT * NN * DD * 2);
  int*      cnt   = (int*)alloc((size_t)TT * NN * 4);
  int*      esw   = (int*)alloc((size_t)TT * NN * 2 * CAP * 4);
  uint16_t* WpHi  = (uint16_t*)alloc(2048 * 8 * 2);
  uint16_t* WpLo  = (uint16_t*)alloc(2048 * 8 * 2);
  uint16_t* QHi   = (uint16_t*)alloc(9216 * 8 * 2);
  float*    biasP = (float*)alloc(576 * 4);
  float*    parts = (float*)alloc((size_t)NN * 120 * 4);
  float*    agg   = (float*)alloc(120 * 4);

  hipMemsetAsync(cnt, 0, (size_t)TT * NN * 4, stream);
  k_fill<<<TT * EE / 256, 256, 0, stream>>>(dstA, cnt, esw);
  k_sortconv<<<TT * NN / 256, 256, 0, stream>>>(cnt, esw, srcA, ew);
  k_prep<<<47, 256, 0, stream>>>(Wp, Wq, Wk, Wv, bq, bk, bv, WpHi, WpLo, QHi, biasP);
  k_gather<<<TT * NN * 16 / 256, 256, 0, stream>>>(node_ids, emb, xA);
  k_prop<<<2048, 256, 0, stream>>>(xA, xB, cnt, esw, WpHi, WpLo, bp, 0);
  k_prop<<<2048, 256, 0, stream>>>(xB, xA, cnt, esw, WpHi, WpLo, bp, 0);
  k_prop<<<2048, 256, 0, stream>>>(xA, xB, cnt, esw, WpHi, WpLo, bp, 1);
  k_attn<<<NN, 256, 0, stream>>>(xB, QHi, biasP, parts);
  k_reduce<<<120, 256, 0, stream>>>(parts, agg);
  k_final<<<1, 128, 0, stream>>>(agg, Wo, bo, (float*)d_out);
}